// Round 2
// baseline (327.318 us; speedup 1.0000x reference)
//
#include <hip/hip_runtime.h>

#define B_ROWS 65536
#define DDIM   256
#define KEMB   1024
#define LRC    0.05f
#define BM 128

typedef __attribute__((ext_vector_type(8))) _Float16 half8;
typedef __attribute__((ext_vector_type(4))) float f32x4;

// ---- workspace layout (bytes) ----
#define SX_OFF    0u            // 1 MB fp32 [K][D]
#define CNT_OFF   1048576u      // 4 KB int [K]
#define SUMS_OFF  1052672u      // 640 B: [1]=commit,[2]=som,[8..71]=xsq slots
#define ESQ_OFF   1053312u      // 4 KB fp32 [K]
#define CUR_OFF   1057408u      // 4 KB int [K]
#define NMIN_OFF  1061504u      // int [B] = 256 KB
#define ROWS_OFF  1585792u      // 256 KB int [B]
#define EH_OFF    1847936u      // 512 KB f16 [K][D]

static __device__ __forceinline__ unsigned short f2h(float f) {
  _Float16 h = (_Float16)f;
  return *(unsigned short*)&h;
}
static __device__ __forceinline__ float h2f(unsigned short u) {
  _Float16 h = *(_Float16*)&u;
  return (float)h;
}
static __device__ __forceinline__ void glds16(const void* g, void* l) {
  __builtin_amdgcn_global_load_lds(
      (const __attribute__((address_space(1))) unsigned int*)g,
      (__attribute__((address_space(3))) unsigned int*)l, 16, 0, 0);
}

// ---------------- convert: X->hi/lo f16 into out region; E->Eh f16; esq; |x|^2 ----
__global__ __launch_bounds__(256) void convert_kernel(
    const float* __restrict__ X, const float* __restrict__ E,
    unsigned short* __restrict__ outU, unsigned short* __restrict__ Eh,
    float* __restrict__ esq, double* __restrict__ sums) {
  __shared__ float red[256];
  const size_t nX8 = (size_t)B_ROWS * DDIM / 8;
  size_t i = (size_t)blockIdx.x * 256 + threadIdx.x;
  bool isX = (i < nX8);
  const float* src;
  unsigned short *dh, *dl = nullptr;
  if (isX) {
    size_t off = i * 8;
    src = X + off;
    dh = outU + (off >> 8) * 512 + (off & 255);
    dl = dh + 256;
  } else {
    size_t off = (i - nX8) * 8;
    src = E + off;
    dh = Eh + off;
  }
  const float4 v0 = *(const float4*)src;
  const float4 v1 = *(const float4*)(src + 4);
  float f[8] = {v0.x, v0.y, v0.z, v0.w, v1.x, v1.y, v1.z, v1.w};
  unsigned short h[8], l[8];
  float part = 0.f;
#pragma unroll
  for (int j = 0; j < 8; ++j) {
    h[j] = f2h(f[j]);
    l[j] = f2h(f[j] - h2f(h[j]));
    part += f[j] * f[j];
  }
  *(uint4*)dh = *(const uint4*)h;
  if (isX) *(uint4*)dl = *(const uint4*)l;
  if (!isX) {
    float s = part;
    for (int off = 16; off > 0; off >>= 1) s += __shfl_down(s, off, 32);
    if ((threadIdx.x & 31) == 0) esq[(i - nX8) >> 5] = s;
  }
  red[threadIdx.x] = isX ? part : 0.f;
  __syncthreads();
  for (int s = 128; s > 0; s >>= 1) {
    if (threadIdx.x < s) red[threadIdx.x] += red[threadIdx.x + s];
    __syncthreads();
  }
  if (threadIdx.x == 0 && isX)
    atomicAdd(&sums[8 + ((int)blockIdx.x & 63)], (double)red[0]);
}

// ---------------- A: X-persistent-LDS dist-GEMM, register-pipelined --------------
// Round-1 post-mortem: FETCH dropped 7x but dur unchanged (132us, MfmaUtil 20%) —
// latency-serialized: 1 wave/SIMD + lgkmcnt(0)-then-MFMA lockstep. Fix: register
// double-buffer the 12 fragment ds_reads (issue for step s+1 BEFORE step-s MFMAs),
// E ring of 3, raw s_barrier with vmcnt(0)-only drain (2 L2 loads issued ~600cyc
// earlier -> free). LDS pipe (576cyc/step) and MFMA pipe (620cyc/step) now overlap.
__global__ __launch_bounds__(256, 1) void gemm_argmin_kernel(
    const unsigned short* __restrict__ XhlU, const unsigned short* __restrict__ EhW,
    const float* __restrict__ esq, const float* __restrict__ Ef,
    int* __restrict__ nmin, int* __restrict__ counts, float* __restrict__ zq) {
  __shared__ __align__(16) unsigned short sX[2][8][512][8];  // 131072 B persistent X
  __shared__ __align__(16) unsigned short sE[3][512][8];     // 24576 B E ring

  const int tid  = threadIdx.x;
  const int lane = tid & 63, w = tid >> 6;
  const int lrow = lane & 15;
  const int qidx = lane >> 4;
  const int rowbase = (w >> 1) * 64;
  const int colb    = (w & 1) * 64;
  const int bm0 = (int)blockIdx.x * BM;

  // per-thread E-stage invariants
  int ec_row[2], ec_q8[2];
#pragma unroll
  for (int j = 0; j < 2; ++j) {
    const int c = j * 256 + tid;
    ec_row[j] = c >> 2;
    ec_q8[j]  = ((c & 3) ^ ((ec_row[j] >> 1) & 3)) * 8;
  }

  // ---- prologue: stage E(step0)->buf0, E(step1)->buf1, then full X tile ----
#pragma unroll
  for (int j = 0; j < 2; ++j)
    glds16(EhW + (size_t)ec_row[j] * DDIM + ec_q8[j], (char*)&sE[0][j * 256 + tid][0]);
#pragma unroll
  for (int j = 0; j < 2; ++j)
    glds16(EhW + (size_t)ec_row[j] * DDIM + 32 + ec_q8[j], (char*)&sE[1][j * 256 + tid][0]);
#pragma unroll
  for (int it = 0; it < 32; ++it) {
    const int c    = it * 256 + tid;
    const int tile = c >> 12;          // 0: X hi, 1: X lo
    const int kcc  = (c >> 9) & 7;
    const int cc   = c & 511;
    const int row  = cc >> 2;
    const int q    = (cc & 3) ^ ((row >> 1) & 3);
    glds16(XhlU + (size_t)(bm0 + row) * 512 + tile * 256 + kcc * 32 + q * 8,
           (char*)sX + (size_t)c * 16);
  }

  float rbest[16];
  int   ridx[16];
#pragma unroll
  for (int i = 0; i < 16; ++i) { rbest[i] = 3.4e38f; ridx[i] = 0; }

  // per-thread fragment LDS row indices (fixed across steps)
  int ra[4], rb[4];
#pragma unroll
  for (int t = 0; t < 4; ++t) {
    const int m = rowbase + t * 16 + lrow;
    ra[t] = (m << 2) | (qidx ^ ((m >> 1) & 3));
    const int n = colb + t * 16 + lrow;
    rb[t] = (n << 2) | (qidx ^ ((n >> 1) & 3));
  }

  __syncthreads();   // full drain: X + E0 + E1 resident

  // preload step-0 fragments into set A
  half8 fA0[4], fA1[4], fB[4], gA0[4], gA1[4], gB[4];
#pragma unroll
  for (int t = 0; t < 4; ++t) {
    fA0[t] = *(const half8*)&sX[0][0][ra[t]][0];
    fA1[t] = *(const half8*)&sX[1][0][ra[t]][0];
    fB[t]  = *(const half8*)&sE[0][rb[t]][0];
  }

  f32x4 acc[4][4];
  int rbuf = 1;   // sE buf holding frags for step s+1
  int wbuf = 2;   // sE buf to stage step s+2 into

#define PIPE_STEP(c0, c1, cB, n0, n1, nB, S)                                     \
  {                                                                              \
    const int s_ = (S);                                                          \
    if ((s_ & 7) == 0) {                                                         \
      _Pragma("unroll") for (int i_ = 0; i_ < 4; ++i_)                           \
        _Pragma("unroll") for (int j_ = 0; j_ < 4; ++j_)                         \
          acc[i_][j_] = (f32x4){0.f, 0.f, 0.f, 0.f};                             \
    }                                                                            \
    if (s_ + 2 < 64) {  /* stage E(s+2) early: drained at this step's barrier */ \
      const int se_ = s_ + 2, nnt_ = se_ >> 3, nk_ = se_ & 7;                    \
      _Pragma("unroll") for (int j_ = 0; j_ < 2; ++j_) {                         \
        const int c_ = j_ * 256 + tid;                                           \
        glds16(EhW + (size_t)(nnt_ * BM + ec_row[j_]) * DDIM + nk_ * 32 +        \
                   ec_q8[j_],                                                    \
               (char*)&sE[wbuf][c_][0]);                                         \
      }                                                                          \
    }                                                                            \
    if (s_ + 1 < 64) {  /* prefetch frags(s+1): lgkm wait lands next step */     \
      const int k1_ = (s_ + 1) & 7;                                              \
      _Pragma("unroll") for (int t_ = 0; t_ < 4; ++t_) {                         \
        n0[t_] = *(const half8*)&sX[0][k1_][ra[t_]][0];                          \
        n1[t_] = *(const half8*)&sX[1][k1_][ra[t_]][0];                          \
        nB[t_] = *(const half8*)&sE[rbuf][rb[t_]][0];                            \
      }                                                                          \
    }                                                                            \
    _Pragma("unroll") for (int tr_ = 0; tr_ < 4; ++tr_)                          \
      _Pragma("unroll") for (int tc_ = 0; tc_ < 4; ++tc_)                        \
        acc[tr_][tc_] = __builtin_amdgcn_mfma_f32_16x16x32_f16(                  \
            c0[tr_], cB[tc_], acc[tr_][tc_], 0, 0, 0);                           \
    _Pragma("unroll") for (int tr_ = 0; tr_ < 4; ++tr_)                          \
      _Pragma("unroll") for (int tc_ = 0; tc_ < 4; ++tc_)                        \
        acc[tr_][tc_] = __builtin_amdgcn_mfma_f32_16x16x32_f16(                  \
            c1[tr_], cB[tc_], acc[tr_][tc_], 0, 0, 0);                           \
    if ((s_ & 7) == 7) { /* end of nt group: fold dists into running argmin */   \
      const int nt_ = s_ >> 3;                                                   \
      _Pragma("unroll") for (int tc_ = 0; tc_ < 4; ++tc_) {                      \
        const int col_ = nt_ * BM + colb + tc_ * 16 + lrow;                      \
        const float eq_ = esq[col_];                                             \
        _Pragma("unroll") for (int tr_ = 0; tr_ < 4; ++tr_)                      \
          _Pragma("unroll") for (int rr_ = 0; rr_ < 4; ++rr_) {                  \
            float d_ = eq_ - 2.0f * acc[tr_][tc_][rr_];                          \
            const int sl_ = tr_ * 4 + rr_;                                       \
            if (d_ < rbest[sl_]) { rbest[sl_] = d_; ridx[sl_] = col_; }          \
          }                                                                      \
      }                                                                          \
    }                                                                            \
    rbuf = (rbuf == 2) ? 0 : rbuf + 1;                                           \
    wbuf = (wbuf == 2) ? 0 : wbuf + 1;                                           \
    asm volatile("s_waitcnt vmcnt(0)" ::: "memory"); /* own 2 E loads, ~free */  \
    __builtin_amdgcn_s_barrier();                                                \
  }

  for (int sp = 0; sp < 32; ++sp) {
    const int s0 = sp * 2;
    PIPE_STEP(fA0, fA1, fB, gA0, gA1, gB, s0);
    PIPE_STEP(gA0, gA1, gB, fA0, fA1, fB, s0 + 1);
  }
#undef PIPE_STEP

  __syncthreads();
  // ---- block-local argmin reduce (scratch in sE), fused hist (scratch in sX) --
  float* cdd = (float*)&sE[0][0][0];        // [2][128]
  int*   cdi = (int*)(cdd + 256);           // [2][128]
  int*   snm = cdi + 256;                   // [128]
  int*   h   = (int*)&sX[0][0][0][0];       // [1024]

#pragma unroll
  for (int i = 0; i < 4; ++i) h[tid + i * 256] = 0;

#pragma unroll
  for (int slot = 0; slot < 16; ++slot) {
    float bd = rbest[slot];
    int   bi = ridx[slot];
#pragma unroll
    for (int off = 1; off < 16; off <<= 1) {
      float od = __shfl_xor(bd, off, 64);
      int   oi = __shfl_xor(bi, off, 64);
      if (od < bd || (od == bd && oi < bi)) { bd = od; bi = oi; }
    }
    if (lrow == 0) {
      const int row = rowbase + (slot >> 2) * 16 + (lane >> 4) * 4 + (slot & 3);
      cdd[(w & 1) * 128 + row] = bd;
      cdi[(w & 1) * 128 + row] = bi;
    }
  }
  __syncthreads();
  if (tid < BM) {
    float d0 = cdd[tid], d1 = cdd[128 + tid];
    int   i0 = cdi[tid], i1 = cdi[128 + tid];
    int bi = (d1 < d0 || (d1 == d0 && i1 < i0)) ? i1 : i0;
    nmin[bm0 + tid] = bi;
    snm[tid] = bi;
    atomicAdd(&h[bi], 1);
  }
  __syncthreads();
#pragma unroll
  for (int i = 0; i < 4; ++i) {
    int v = h[tid + i * 256];
    if (v) atomicAdd(&counts[tid + i * 256], v);
  }
  // ---- fused zq gather: wave w -> rows [w*32, w*32+32). E is L2-resident. ----
  const int r0 = w * 32;
#pragma unroll 4
  for (int r = 0; r < 32; ++r) {
    const int k = snm[r0 + r];
    const float4 v = *(const float4*)(Ef + (size_t)k * DDIM + lane * 4);
    *(float4*)(zq + (size_t)(bm0 + r0 + r) * DDIM + lane * 4) = v;
  }
}

// ---------------- scan ----------------
__global__ __launch_bounds__(1024) void scan_kernel(
    const int* __restrict__ counts, int* __restrict__ cur) {
  __shared__ int tmp[KEMB];
  int tid = threadIdx.x;
  int v = counts[tid];
  tmp[tid] = v;
  __syncthreads();
  for (int off = 1; off < 1024; off <<= 1) {
    int u = (tid >= off) ? tmp[tid - off] : 0;
    __syncthreads();
    tmp[tid] += u;
    __syncthreads();
  }
  cur[tid] = tmp[tid] - v;
}

// ---------------- scatter: counting-sort row ids by k ----------------
__global__ __launch_bounds__(1024) void scatter_kernel(
    const int* __restrict__ nm, int* __restrict__ cur,
    int* __restrict__ rows) {
  __shared__ int lcnt[KEMB], lbase[KEMB], lrank[KEMB];
  int tid = threadIdx.x;
  lcnt[tid] = 0; lrank[tid] = 0;
  __syncthreads();
  int b = blockIdx.x * 1024 + tid;
  int k = nm[b];
  atomicAdd(&lcnt[k], 1);
  __syncthreads();
  if (lcnt[tid] > 0) lbase[tid] = atomicAdd(&cur[tid], lcnt[tid]);
  __syncthreads();
  int r = atomicAdd(&lrank[k], 1);
  rows[lbase[k] + r] = b;
}

// ---------------- sxsum: segment-sum sorted chunks into SX ----------------
__global__ __launch_bounds__(256) void sxsum_kernel(
    const int* __restrict__ rows, const int* __restrict__ nm,
    const float* __restrict__ X, float* __restrict__ SX) {
  __shared__ int sb[64], sk[64];
  int tid = threadIdx.x;
  int p0 = blockIdx.x * 64;
  if (tid < 64) sb[tid] = rows[p0 + tid];
  __syncthreads();
  if (tid < 64) sk[tid] = nm[sb[tid]];
  __syncthreads();
  float acc = 0.f;
  int kprev = sk[0];
  for (int i = 0; i < 64; ++i) {
    int k = sk[i];
    if (k != kprev) {
      atomicAdd(&SX[(size_t)kprev * DDIM + tid], acc);
      acc = 0.f;
      kprev = k;
    }
    acc += X[(size_t)sb[i] * DDIM + tid];
  }
  atomicAdd(&SX[(size_t)kprev * DDIM + tid], acc);
}

// ---------------- stencil: new_embeddings + loss partials ----------------
__global__ __launch_bounds__(256) void stencil_kernel(
    const float* __restrict__ E, const float* __restrict__ SX,
    const int* __restrict__ counts, const float* __restrict__ esq,
    double* __restrict__ sums, float* __restrict__ out) {
  __shared__ float redc[256], reds[256];
  int k = blockIdx.x, t = threadIdx.x;
  int kx = k >> 5, ky = k & 31;
  int j1 = (kx >= 1)  ? k - 32 : k;
  int j2 = (kx <= 30) ? k + 32 : k;
  int j3 = (ky >= 1)  ? k - 1  : k;
  int j4 = (ky <= 30) ? k + 1  : k;
  int fU = (kx < 31) ? k + 32 : k;
  int fD = (kx > 0)  ? k - 32 : k;
  int fL = (ky > 0)  ? k - 1  : k;
  int fR = (ky < 31) ? k + 1  : k;

  float e   = E[(size_t)k * DDIM + t];
  float sxk = SX[(size_t)k * DDIM + t];
  float Tk = sxk - (float)counts[k] * e;
  float T1 = SX[(size_t)j1 * DDIM + t] - (float)counts[j1] * E[(size_t)j1 * DDIM + t];
  float T2 = SX[(size_t)j2 * DDIM + t] - (float)counts[j2] * E[(size_t)j2 * DDIM + t];
  float T3 = SX[(size_t)j3 * DDIM + t] - (float)counts[j3] * E[(size_t)j3 * DDIM + t];
  float T4 = SX[(size_t)j4 * DDIM + t] - (float)counts[j4] * E[(size_t)j4 * DDIM + t];
  float v = e + LRC * Tk + 0.5f * LRC * (T1 + T2 + T3 + T4);
  out[(size_t)B_ROWS * DDIM + 2 + (size_t)k * DDIM + t] = v;

  float eU = E[(size_t)fU * DDIM + t], eD = E[(size_t)fD * DDIM + t];
  float eL = E[(size_t)fL * DDIM + t], eR = E[(size_t)fR * DDIM + t];
  float cp = -2.f * sxk * e;
  float sp = -2.f * sxk * (eU + eD + eL + eR);
  if (t == 0) {
    float ck = (float)counts[k];
    cp += ck * esq[k];
    sp += ck * (esq[fU] + esq[fD] + esq[fL] + esq[fR]);
  }
  redc[t] = cp; reds[t] = sp;
  __syncthreads();
  for (int s = 128; s > 0; s >>= 1) {
    if (t < s) { redc[t] += redc[t + s]; reds[t] += reds[t + s]; }
    __syncthreads();
  }
  if (t == 0) {
    atomicAdd(&sums[1], (double)redc[0]);
    atomicAdd(&sums[2], (double)reds[0]);
  }
}

// ---------------- finalize losses ----------------
__global__ void finalize_kernel(const double* __restrict__ sums,
                                float* __restrict__ out) {
  double xsq = 0.0;
  for (int s = 0; s < 64; ++s) xsq += sums[8 + s];
  out[(size_t)B_ROWS * DDIM]     = (float)((xsq + sums[1]) / ((double)B_ROWS * DDIM));
  out[(size_t)B_ROWS * DDIM + 1] =
      (float)((4.0 * xsq + sums[2]) / ((double)B_ROWS * 4.0 * DDIM));
}

extern "C" void kernel_launch(void* const* d_in, const int* in_sizes, int n_in,
                              void* d_out, int out_size, void* d_ws, size_t ws_size,
                              hipStream_t stream) {
  const float* X = (const float*)d_in[0];
  const float* E = (const float*)d_in[1];
  float* out = (float*)d_out;
  unsigned short* outU = (unsigned short*)d_out;
  char* ws = (char*)d_ws;

  float*          SX   = (float*)(ws + SX_OFF);
  int*            cnts = (int*)(ws + CNT_OFF);
  double*         sums = (double*)(ws + SUMS_OFF);
  float*          esq  = (float*)(ws + ESQ_OFF);
  int*            cur  = (int*)(ws + CUR_OFF);
  int*            nm   = (int*)(ws + NMIN_OFF);
  int*            rows = (int*)(ws + ROWS_OFF);
  unsigned short* EhW  = (unsigned short*)(ws + EH_OFF);

  hipMemsetAsync(ws, 0, ESQ_OFF, stream);   // SX + counts + sums

  convert_kernel<<<(B_ROWS * (DDIM / 8) + KEMB * (DDIM / 8)) / 256, 256, 0, stream>>>(
      X, E, outU, EhW, esq, sums);
  gemm_argmin_kernel<<<B_ROWS / BM, 256, 0, stream>>>(outU, EhW, esq, E, nm, cnts, out);
  scan_kernel<<<1, 1024, 0, stream>>>(cnts, cur);
  scatter_kernel<<<B_ROWS / 1024, 1024, 0, stream>>>(nm, cur, rows);
  sxsum_kernel<<<B_ROWS / 64, 256, 0, stream>>>(rows, nm, X, SX);
  stencil_kernel<<<KEMB, 256, 0, stream>>>(E, SX, cnts, esq, sums, out);
  finalize_kernel<<<1, 1, 0, stream>>>(sums, out);
}

// Round 3
// 281.886 us; speedup vs baseline: 1.1612x; 1.1612x over previous
//
#include <hip/hip_runtime.h>

#define B_ROWS 65536
#define DDIM   256
#define KEMB   1024
#define LRC    0.05f
#define BM 64
#define BN 128

typedef __attribute__((ext_vector_type(8))) _Float16 half8;
typedef __attribute__((ext_vector_type(4))) float f32x4;

// ---- workspace layout (bytes) ----
#define SX_OFF    0u            // 1 MB fp32 [K][D]
#define CNT_OFF   1048576u      // 4 KB int [K]
#define SUMS_OFF  1052672u      // 640 B: [1]=commit,[2]=som,[8..71]=xsq slots
#define ESQ_OFF   1053312u      // 4 KB fp32 [K]
#define CUR_OFF   1057408u      // 4 KB int [K]
#define NMIN_OFF  1061504u      // int [B] = 256 KB
#define ROWS_OFF  1585792u      // 256 KB int [B]
#define EH_OFF    1847936u      // 512 KB f16 [K][D]

static __device__ __forceinline__ unsigned short f2h(float f) {
  _Float16 h = (_Float16)f;
  return *(unsigned short*)&h;
}
static __device__ __forceinline__ float h2f(unsigned short u) {
  _Float16 h = *(_Float16*)&u;
  return (float)h;
}
static __device__ __forceinline__ void glds16(const void* g, void* l) {
  __builtin_amdgcn_global_load_lds(
      (const __attribute__((address_space(1))) unsigned int*)g,
      (__attribute__((address_space(3))) unsigned int*)l, 16, 0, 0);
}

// ---------------- convert: X->hi/lo f16 into out region; E->Eh f16; esq; |x|^2 ----
__global__ __launch_bounds__(256) void convert_kernel(
    const float* __restrict__ X, const float* __restrict__ E,
    unsigned short* __restrict__ outU, unsigned short* __restrict__ Eh,
    float* __restrict__ esq, double* __restrict__ sums) {
  __shared__ float red[256];
  const size_t nX8 = (size_t)B_ROWS * DDIM / 8;
  size_t i = (size_t)blockIdx.x * 256 + threadIdx.x;
  bool isX = (i < nX8);
  const float* src;
  unsigned short *dh, *dl = nullptr;
  if (isX) {
    size_t off = i * 8;
    src = X + off;
    dh = outU + (off >> 8) * 512 + (off & 255);
    dl = dh + 256;
  } else {
    size_t off = (i - nX8) * 8;
    src = E + off;
    dh = Eh + off;
  }
  const float4 v0 = *(const float4*)src;
  const float4 v1 = *(const float4*)(src + 4);
  float f[8] = {v0.x, v0.y, v0.z, v0.w, v1.x, v1.y, v1.z, v1.w};
  unsigned short h[8], l[8];
  float part = 0.f;
#pragma unroll
  for (int j = 0; j < 8; ++j) {
    h[j] = f2h(f[j]);
    l[j] = f2h(f[j] - h2f(h[j]));
    part += f[j] * f[j];
  }
  *(uint4*)dh = *(const uint4*)h;
  if (isX) *(uint4*)dl = *(const uint4*)l;
  if (!isX) {
    float s = part;
    for (int off = 16; off > 0; off >>= 1) s += __shfl_down(s, off, 32);
    if ((threadIdx.x & 31) == 0) esq[(i - nX8) >> 5] = s;
  }
  red[threadIdx.x] = isX ? part : 0.f;
  __syncthreads();
  for (int s = 128; s > 0; s >>= 1) {
    if (threadIdx.x < s) red[threadIdx.x] += red[threadIdx.x + s];
    __syncthreads();
  }
  if (threadIdx.x == 0 && isX)
    atomicAdd(&sums[8 + ((int)blockIdx.x & 63)], (double)red[0]);
}

// ---------------- A: X-persistent-LDS dist-GEMM, BM=64 / 2 blocks per CU --------
// Round-2 post-mortem: intra-block reg-pipelining regressed (runtime ring idx ->
// VALU bloat; compiler sank the prefetch). Round-1 lockstep is the best 1-block
// schedule (132us, ~1250cyc/step overhead). Fix = TLP: BM=64 -> LDS 80KB ->
// 2 independent blocks/CU whose barriers interleave (m114 co-scheduling).
// Same known-good step scheme as round 1: stage next E, ds_read frags, MFMA,
// __syncthreads. Numerically identical per output row.
__global__ __launch_bounds__(256, 2) void gemm_argmin_kernel(
    const unsigned short* __restrict__ XhlU, const unsigned short* __restrict__ EhW,
    const float* __restrict__ esq, const float* __restrict__ Ef,
    int* __restrict__ nmin, int* __restrict__ counts, float* __restrict__ zq) {
  __shared__ __align__(16) unsigned short sX[2][8][256][8];  // 65536 B persistent X
  __shared__ __align__(16) unsigned short sE[2][512][8];     // 16384 B E dbuf

  const int tid  = threadIdx.x;
  const int lane = tid & 63, w = tid >> 6;
  const int lrow = lane & 15;
  const int qidx = lane >> 4;
  const int rowbase = (w >> 1) * 32;   // 2x2 wave grid: 32 rows x 64 cols each
  const int colb    = (w & 1) * 64;
  const int bm0 = (int)blockIdx.x * BM;

  // per-thread E-stage invariants (E tile = BN x 32k = 512 chunks)
  int ec_row[2], ec_q8[2];
#pragma unroll
  for (int j = 0; j < 2; ++j) {
    const int c = j * 256 + tid;
    ec_row[j] = c >> 2;
    ec_q8[j]  = ((c & 3) ^ ((ec_row[j] >> 1) & 3)) * 8;
  }

  // ---- prologue: stage E(step0) then full X tile (once) ----
#pragma unroll
  for (int j = 0; j < 2; ++j)
    glds16(EhW + (size_t)ec_row[j] * DDIM + ec_q8[j], (char*)&sE[0][j * 256 + tid][0]);
#pragma unroll
  for (int it = 0; it < 16; ++it) {
    const int c    = it * 256 + tid;
    const int tile = c >> 11;          // 0: X hi, 1: X lo
    const int kcc  = (c >> 8) & 7;
    const int cc   = c & 255;
    const int row  = cc >> 2;
    const int q    = (cc & 3) ^ ((row >> 1) & 3);
    glds16(XhlU + (size_t)(bm0 + row) * 512 + tile * 256 + kcc * 32 + q * 8,
           (char*)sX + (size_t)c * 16);
  }

  float rbest[8];
  int   ridx[8];
#pragma unroll
  for (int i = 0; i < 8; ++i) { rbest[i] = 3.4e38f; ridx[i] = 0; }

  // per-thread fragment LDS chunk indices (fixed across steps)
  int ra[2], rb[4];
#pragma unroll
  for (int t = 0; t < 2; ++t) {
    const int m = rowbase + t * 16 + lrow;
    ra[t] = (m << 2) | (qidx ^ ((m >> 1) & 3));
  }
#pragma unroll
  for (int t = 0; t < 4; ++t) {
    const int n = colb + t * 16 + lrow;
    rb[t] = (n << 2) | (qidx ^ ((n >> 1) & 3));
  }

  __syncthreads();   // X + E0 resident

  for (int nt = 0; nt < 8; ++nt) {
    f32x4 acc[2][4];
#pragma unroll
    for (int i = 0; i < 2; ++i)
#pragma unroll
      for (int j = 0; j < 4; ++j) acc[i][j] = (f32x4){0.f, 0.f, 0.f, 0.f};

#pragma unroll
    for (int kcc = 0; kcc < 8; ++kcc) {
      const int s   = nt * 8 + kcc;
      const int cur = s & 1;
      // stage next E tile into the other buffer BEFORE compute (hides latency)
      if (s < 63) {
        const int ns = s + 1;
        const int nnt = ns >> 3, nk = ns & 7;
#pragma unroll
        for (int j = 0; j < 2; ++j) {
          const int c = j * 256 + tid;
          glds16(EhW + (size_t)(nnt * BN + ec_row[j]) * DDIM + nk * 32 + ec_q8[j],
                 (char*)&sE[cur ^ 1][c][0]);
        }
      }
      half8 af0[2], af1[2], bfr[4];
#pragma unroll
      for (int t = 0; t < 2; ++t) {
        af0[t] = *(const half8*)&sX[0][kcc][ra[t]][0];
        af1[t] = *(const half8*)&sX[1][kcc][ra[t]][0];
      }
#pragma unroll
      for (int t = 0; t < 4; ++t) bfr[t] = *(const half8*)&sE[cur][rb[t]][0];
#pragma unroll
      for (int tr = 0; tr < 2; ++tr)
#pragma unroll
        for (int tc = 0; tc < 4; ++tc)
          acc[tr][tc] = __builtin_amdgcn_mfma_f32_16x16x32_f16(
              af0[tr], bfr[tc], acc[tr][tc], 0, 0, 0);
#pragma unroll
      for (int tr = 0; tr < 2; ++tr)
#pragma unroll
        for (int tc = 0; tc < 4; ++tc)
          acc[tr][tc] = __builtin_amdgcn_mfma_f32_16x16x32_f16(
              af1[tr], bfr[tc], acc[tr][tc], 0, 0, 0);
      // single barrier/step: protects E dbuf WAR + drains own stage (vmcnt 0)
      __syncthreads();
    }
    // epilogue: argmin update (registers only; safe across the barrier)
#pragma unroll
    for (int tc = 0; tc < 4; ++tc) {
      const int col = nt * BN + colb + tc * 16 + lrow;
      const float eq = esq[col];
#pragma unroll
      for (int tr = 0; tr < 2; ++tr)
#pragma unroll
        for (int rr = 0; rr < 4; ++rr) {
          float d = eq - 2.0f * acc[tr][tc][rr];
          const int slot = tr * 4 + rr;
          if (d < rbest[slot]) { rbest[slot] = d; ridx[slot] = col; }
        }
    }
  }

  // ---- block-local argmin reduce (scratch in sE), fused hist (scratch in sX) --
  float* cdd = (float*)&sE[0][0][0];        // [2][64]
  int*   cdi = (int*)(cdd + 128);           // [2][64]
  int*   snm = cdi + 128;                   // [64]
  int*   h   = (int*)&sX[0][0][0][0];       // [1024]

#pragma unroll
  for (int i = 0; i < 4; ++i) h[tid + i * 256] = 0;

#pragma unroll
  for (int slot = 0; slot < 8; ++slot) {
    float bd = rbest[slot];
    int   bi = ridx[slot];
#pragma unroll
    for (int off = 1; off < 16; off <<= 1) {
      float od = __shfl_xor(bd, off, 64);
      int   oi = __shfl_xor(bi, off, 64);
      if (od < bd || (od == bd && oi < bi)) { bd = od; bi = oi; }
    }
    if (lrow == 0) {
      const int row = rowbase + (slot >> 2) * 16 + (lane >> 4) * 4 + (slot & 3);
      cdd[(w & 1) * 64 + row] = bd;
      cdi[(w & 1) * 64 + row] = bi;
    }
  }
  __syncthreads();
  if (tid < BM) {
    float d0 = cdd[tid], d1 = cdd[64 + tid];
    int   i0 = cdi[tid], i1 = cdi[64 + tid];
    int bi = (d1 < d0 || (d1 == d0 && i1 < i0)) ? i1 : i0;
    nmin[bm0 + tid] = bi;
    snm[tid] = bi;
    atomicAdd(&h[bi], 1);
  }
  __syncthreads();
#pragma unroll
  for (int i = 0; i < 4; ++i) {
    int v = h[tid + i * 256];
    if (v) atomicAdd(&counts[tid + i * 256], v);
  }
  // ---- fused zq gather: wave w -> rows [w*16, w*16+16). E is L2-resident. ----
  const int r0 = w * 16;
#pragma unroll 4
  for (int r = 0; r < 16; ++r) {
    const int k = snm[r0 + r];
    const float4 v = *(const float4*)(Ef + (size_t)k * DDIM + lane * 4);
    *(float4*)(zq + (size_t)(bm0 + r0 + r) * DDIM + lane * 4) = v;
  }
}

// ---------------- scan ----------------
__global__ __launch_bounds__(1024) void scan_kernel(
    const int* __restrict__ counts, int* __restrict__ cur) {
  __shared__ int tmp[KEMB];
  int tid = threadIdx.x;
  int v = counts[tid];
  tmp[tid] = v;
  __syncthreads();
  for (int off = 1; off < 1024; off <<= 1) {
    int u = (tid >= off) ? tmp[tid - off] : 0;
    __syncthreads();
    tmp[tid] += u;
    __syncthreads();
  }
  cur[tid] = tmp[tid] - v;
}

// ---------------- scatter: counting-sort row ids by k ----------------
__global__ __launch_bounds__(1024) void scatter_kernel(
    const int* __restrict__ nm, int* __restrict__ cur,
    int* __restrict__ rows) {
  __shared__ int lcnt[KEMB], lbase[KEMB], lrank[KEMB];
  int tid = threadIdx.x;
  lcnt[tid] = 0; lrank[tid] = 0;
  __syncthreads();
  int b = blockIdx.x * 1024 + tid;
  int k = nm[b];
  atomicAdd(&lcnt[k], 1);
  __syncthreads();
  if (lcnt[tid] > 0) lbase[tid] = atomicAdd(&cur[tid], lcnt[tid]);
  __syncthreads();
  int r = atomicAdd(&lrank[k], 1);
  rows[lbase[k] + r] = b;
}

// ---------------- sxsum: segment-sum sorted chunks into SX ----------------
__global__ __launch_bounds__(256) void sxsum_kernel(
    const int* __restrict__ rows, const int* __restrict__ nm,
    const float* __restrict__ X, float* __restrict__ SX) {
  __shared__ int sb[64], sk[64];
  int tid = threadIdx.x;
  int p0 = blockIdx.x * 64;
  if (tid < 64) sb[tid] = rows[p0 + tid];
  __syncthreads();
  if (tid < 64) sk[tid] = nm[sb[tid]];
  __syncthreads();
  float acc = 0.f;
  int kprev = sk[0];
  for (int i = 0; i < 64; ++i) {
    int k = sk[i];
    if (k != kprev) {
      atomicAdd(&SX[(size_t)kprev * DDIM + tid], acc);
      acc = 0.f;
      kprev = k;
    }
    acc += X[(size_t)sb[i] * DDIM + tid];
  }
  atomicAdd(&SX[(size_t)kprev * DDIM + tid], acc);
}

// ---------------- stencil: new_embeddings + loss partials ----------------
__global__ __launch_bounds__(256) void stencil_kernel(
    const float* __restrict__ E, const float* __restrict__ SX,
    const int* __restrict__ counts, const float* __restrict__ esq,
    double* __restrict__ sums, float* __restrict__ out) {
  __shared__ float redc[256], reds[256];
  int k = blockIdx.x, t = threadIdx.x;
  int kx = k >> 5, ky = k & 31;
  int j1 = (kx >= 1)  ? k - 32 : k;
  int j2 = (kx <= 30) ? k + 32 : k;
  int j3 = (ky >= 1)  ? k - 1  : k;
  int j4 = (ky <= 30) ? k + 1  : k;
  int fU = (kx < 31) ? k + 32 : k;
  int fD = (kx > 0)  ? k - 32 : k;
  int fL = (ky > 0)  ? k - 1  : k;
  int fR = (ky < 31) ? k + 1  : k;

  float e   = E[(size_t)k * DDIM + t];
  float sxk = SX[(size_t)k * DDIM + t];
  float Tk = sxk - (float)counts[k] * e;
  float T1 = SX[(size_t)j1 * DDIM + t] - (float)counts[j1] * E[(size_t)j1 * DDIM + t];
  float T2 = SX[(size_t)j2 * DDIM + t] - (float)counts[j2] * E[(size_t)j2 * DDIM + t];
  float T3 = SX[(size_t)j3 * DDIM + t] - (float)counts[j3] * E[(size_t)j3 * DDIM + t];
  float T4 = SX[(size_t)j4 * DDIM + t] - (float)counts[j4] * E[(size_t)j4 * DDIM + t];
  float v = e + LRC * Tk + 0.5f * LRC * (T1 + T2 + T3 + T4);
  out[(size_t)B_ROWS * DDIM + 2 + (size_t)k * DDIM + t] = v;

  float eU = E[(size_t)fU * DDIM + t], eD = E[(size_t)fD * DDIM + t];
  float eL = E[(size_t)fL * DDIM + t], eR = E[(size_t)fR * DDIM + t];
  float cp = -2.f * sxk * e;
  float sp = -2.f * sxk * (eU + eD + eL + eR);
  if (t == 0) {
    float ck = (float)counts[k];
    cp += ck * esq[k];
    sp += ck * (esq[fU] + esq[fD] + esq[fL] + esq[fR]);
  }
  redc[t] = cp; reds[t] = sp;
  __syncthreads();
  for (int s = 128; s > 0; s >>= 1) {
    if (t < s) { redc[t] += redc[t + s]; reds[t] += reds[t + s]; }
    __syncthreads();
  }
  if (t == 0) {
    atomicAdd(&sums[1], (double)redc[0]);
    atomicAdd(&sums[2], (double)reds[0]);
  }
}

// ---------------- finalize losses ----------------
__global__ void finalize_kernel(const double* __restrict__ sums,
                                float* __restrict__ out) {
  double xsq = 0.0;
  for (int s = 0; s < 64; ++s) xsq += sums[8 + s];
  out[(size_t)B_ROWS * DDIM]     = (float)((xsq + sums[1]) / ((double)B_ROWS * DDIM));
  out[(size_t)B_ROWS * DDIM + 1] =
      (float)((4.0 * xsq + sums[2]) / ((double)B_ROWS * 4.0 * DDIM));
}

extern "C" void kernel_launch(void* const* d_in, const int* in_sizes, int n_in,
                              void* d_out, int out_size, void* d_ws, size_t ws_size,
                              hipStream_t stream) {
  const float* X = (const float*)d_in[0];
  const float* E = (const float*)d_in[1];
  float* out = (float*)d_out;
  unsigned short* outU = (unsigned short*)d_out;
  char* ws = (char*)d_ws;

  float*          SX   = (float*)(ws + SX_OFF);
  int*            cnts = (int*)(ws + CNT_OFF);
  double*         sums = (double*)(ws + SUMS_OFF);
  float*          esq  = (float*)(ws + ESQ_OFF);
  int*            cur  = (int*)(ws + CUR_OFF);
  int*            nm   = (int*)(ws + NMIN_OFF);
  int*            rows = (int*)(ws + ROWS_OFF);
  unsigned short* EhW  = (unsigned short*)(ws + EH_OFF);

  hipMemsetAsync(ws, 0, ESQ_OFF, stream);   // SX + counts + sums

  convert_kernel<<<(B_ROWS * (DDIM / 8) + KEMB * (DDIM / 8)) / 256, 256, 0, stream>>>(
      X, E, outU, EhW, esq, sums);
  gemm_argmin_kernel<<<B_ROWS / BM, 256, 0, stream>>>(outU, EhW, esq, E, nm, cnts, out);
  scan_kernel<<<1, 1024, 0, stream>>>(cnts, cur);
  scatter_kernel<<<B_ROWS / 1024, 1024, 0, stream>>>(nm, cur, rows);
  sxsum_kernel<<<B_ROWS / 64, 256, 0, stream>>>(rows, nm, X, SX);
  stencil_kernel<<<KEMB, 256, 0, stream>>>(E, SX, cnts, esq, sums, out);
  finalize_kernel<<<1, 1, 0, stream>>>(sums, out);
}